// Round 10
// baseline (161.458 us; speedup 1.0000x reference)
//
#include <hip/hip_runtime.h>

#define DDIM 256
#define HDIM 128
#define KLEN 1024
// 2*log2(e): exp2(SCL*x) == e^{2x}
#define SCL 2.8853900817779268f

// ============ Projection -> Eq/Ek = exp2(SCL * in@W) ============
// v2 (proven 33us): wave-uniform W (scalar s_load path) x per-lane rows.
// Block = 64 rows x 32 h = 4 waves; each wave owns 8 h, each lane owns 1 row.
// A-tile (64 rows x 64 d) in LDS, XOR-swizzled on 16B granules so each
// lane's ds_read_b128 of its own row is <=2-way (free). W operands are
// wave-uniform -> scalar loads, costing no VALU/VMEM/LDS bandwidth.
// Grid 1088 (4.25 blocks/CU): 1024 key blocks (XCD-swizzled) + 64 query.
// Output layouts: Eq row-major [row][128], Ek [b][h][k], exp2 applied.
__global__ __launch_bounds__(256) void proj_kernel(
    const float* __restrict__ queries, const float* __restrict__ keys,
    const float* __restrict__ W_q, const float* __restrict__ W_k,
    float* __restrict__ Eq, float* __restrict__ Ek)
{
    __shared__ union {
        float a[64 * 64];    // 16 KB A-tile (swizzled)
        float t[32][68];     // epilogue transpose staging (keys), pad 64->68
    } sm;

    const int tid  = threadIdx.x;
    const int lane = tid & 63;
    const int wav  = tid >> 6;

    int blk = blockIdx.x;
    bool iskey; int b = 0, kc0 = 0, hb, row0;
    const float* in; const float* W;
    if (blk < 1024) {
        iskey = true;
        int xcd = blk & 7, s = blk >> 3;
        b = ((s >> 6) << 3) | xcd;
        int r6 = s & 63;
        kc0 = (r6 >> 2) << 6;     // 16 k-chunks of 64
        hb  = (r6 & 3) << 5;      // 4 h-chunks of 32
        row0 = b * KLEN + kc0;
        in = keys; W = W_k;
    } else {
        iskey = false;
        int qrb = blk - 1024;     // 0..63
        row0 = (qrb >> 2) << 6;
        hb   = (qrb & 3) << 5;
        in = queries; W = W_q;
    }

    // wave-uniform h-base -> W accesses become scalar loads
    const int hg8 = __builtin_amdgcn_readfirstlane(wav << 3);
    const float* Wu = W + hb + hg8;

    // staging: 4 x 16B granules per thread per 64-d step, coalesced reads
    const int srow = tid >> 4;        // 0..15 (+16*i covers 64 rows)
    const int sgd  = tid & 15;        // 16B granule within 64-d row slice
    const float* gsrc = in + (size_t)(row0 + srow) * DDIM + (sgd << 2);

    float4 pf0 = *(const float4*)(gsrc);
    float4 pf1 = *(const float4*)(gsrc + 16 * DDIM);
    float4 pf2 = *(const float4*)(gsrc + 32 * DDIM);
    float4 pf3 = *(const float4*)(gsrc + 48 * DDIM);

    float acc[8];
    #pragma unroll
    for (int c = 0; c < 8; c++) acc[c] = 0.f;

    // XOR-swizzled LDS write offsets (float index): granule ^= (row & 7)
    const int w0 = (srow)      * 64 + ((sgd ^ ((srow)      & 7)) << 2);
    const int w1 = (srow + 16) * 64 + ((sgd ^ ((srow + 16) & 7)) << 2);
    const int w2 = (srow + 32) * 64 + ((sgd ^ ((srow + 32) & 7)) << 2);
    const int w3 = (srow + 48) * 64 + ((sgd ^ ((srow + 48) & 7)) << 2);

    for (int dt0 = 0; dt0 < DDIM; dt0 += 64) {
        *(float4*)(sm.a + w0) = pf0;
        *(float4*)(sm.a + w1) = pf1;
        *(float4*)(sm.a + w2) = pf2;
        *(float4*)(sm.a + w3) = pf3;
        __syncthreads();
        if (dt0 < DDIM - 64) {        // prefetch next d-tile under compute
            const float* g2 = gsrc + dt0 + 64;
            pf0 = *(const float4*)(g2);
            pf1 = *(const float4*)(g2 + 16 * DDIM);
            pf2 = *(const float4*)(g2 + 32 * DDIM);
            pf3 = *(const float4*)(g2 + 48 * DDIM);
        }
        const float* arow = sm.a + lane * 64;
        const int lx = lane & 7;
        #pragma unroll
        for (int d4 = 0; d4 < 64; d4 += 4) {
            float4 a = *(const float4*)(arow + ((((d4 >> 2)) ^ lx) << 2));
            const float* wr = Wu + (size_t)(dt0 + d4) * HDIM;
            #pragma unroll
            for (int c = 0; c < 8; c++) acc[c] = fmaf(a.x, wr[c],            acc[c]);
            #pragma unroll
            for (int c = 0; c < 8; c++) acc[c] = fmaf(a.y, wr[HDIM + c],     acc[c]);
            #pragma unroll
            for (int c = 0; c < 8; c++) acc[c] = fmaf(a.z, wr[2 * HDIM + c], acc[c]);
            #pragma unroll
            for (int c = 0; c < 8; c++) acc[c] = fmaf(a.w, wr[3 * HDIM + c], acc[c]);
        }
        __syncthreads();   // compute done before next tile overwrites LDS
    }

    float e[8];
    #pragma unroll
    for (int c = 0; c < 8; c++) e[c] = __builtin_amdgcn_exp2f(SCL * acc[c]);

    if (!iskey) {
        float* dst = Eq + (size_t)(row0 + lane) * HDIM + hb + hg8;
        *(float4*)(dst)     = make_float4(e[0], e[1], e[2], e[3]);
        *(float4*)(dst + 4) = make_float4(e[4], e[5], e[6], e[7]);
    } else {
        // transpose 64k x 32h -> t[h][k], then coalesced 256B-row stores
        #pragma unroll
        for (int c = 0; c < 8; c++) sm.t[(wav << 3) + c][lane] = e[c];
        __syncthreads();
        float* dstb = Ek + (size_t)b * HDIM * KLEN + (size_t)hb * KLEN + kc0;
        #pragma unroll
        for (int i = 0; i < 2; i++) {
            int g = tid + (i << 8);
            int h = g >> 4, k4 = (g & 15) << 2;
            float4 o = *(const float4*)(&sm.t[h][k4]);
            *(float4*)(dstb + (size_t)h * KLEN + k4) = o;
        }
    }
}

// ============ FUSED scores + E@V v3 (normalization-free, max-TLP) ============
// R9 lesson: makespan = per-block latency chain; skip alone is neutral at
// 4 blocks/CU. v3: grid 2048 = (16 b x 8 qt x 16 ks of 64 k), 256 thr ->
// 8 blocks/CU = 32 waves/CU (occupancy max; needs VGPR<=64 -> enforced by
// __launch_bounds__(256,8) + 4h-chunk pipeline). Thread = 2q x 1k.
// Phase 1 has ZERO LDS traffic: Ek scalar stream (256B/wave coalesced) +
// eq/w2 uniform global loads (L1-broadcast), keeping the per-CU LDS pipe
// off the critical path at 32 waves. E tile -> el[64][12] (3 KB).
// Phase 2: wave owns 16 k; per k one coalesced 1KB/wave V row + 2
// broadcast b128 el reads -> 32 fma + 8 T-adds. Cross-wave reduce = 4
// barrier-serialized passes into accbuf (8 KB) -> LDS 11.3 KB/block.
// vlen-skip now effective (8 resident blocks smooth the makespan).
// Softmax algebra: Sum(w) const and max-shift cancel in (E@V)/T; |s|<~25
// -> exp fp32-safe. All outputs written unconditionally -> poison-safe.
__global__ __launch_bounds__(256, 8) void score_av_kernel(
    const float* __restrict__ Eq, const float* __restrict__ Ek,
    const float* __restrict__ w_v, const int* __restrict__ valid_lens,
    const float* __restrict__ values,
    float* __restrict__ part, float* __restrict__ Tp)
{
    __shared__ float el[64][12];      // E tile [k][8q], pad 12 (rows 48B)
    __shared__ float accbuf[8][256];  // block O accumulator (8 KB)
    __shared__ float tacc[8];

    const int tid = threadIdx.x;
    const int lane = tid & 63, wav = tid >> 6;
    int blk = blockIdx.x;
    int xcd = blk & 7, s = blk >> 3;          // 0..255
    int b = ((s >> 7) << 3) | xcd;            // XCD-matched to proj's Ek[b]
    int r = s & 127;
    int qt = r >> 4, ks = r & 15;
    int bq0 = b * 64 + qt * 8;
    int k0g = ks << 6;                        // 64-k slice base
    int vlen = valid_lens[b];

    if (k0g >= vlen) {                        // fully-masked slice: zeros
        float4 z = make_float4(0.f, 0.f, 0.f, 0.f);
        #pragma unroll
        for (int e = 0; e < 2; e++) {
            int slot = (tid << 1) | e;        // 512 f4 slots
            int q = slot >> 6, d4 = slot & 63;
            *(float4*)(part + ((size_t)ks * 1024 + bq0 + q) * DDIM + (d4 << 2)) = z;
        }
        if (tid < 8) Tp[(size_t)ks * 1024 + bq0 + tid] = 0.f;
        return;
    }

    // ---- phase 1: thread = 2q x 1k, 128 h, 4h-chunk software pipeline ----
    const int q0 = wav << 1;
    const float* ekp = Ek + (size_t)b * HDIM * KLEN + k0g + lane;  // + h*KLEN
    const float* eqa = Eq + (size_t)(bq0 + q0) * HDIM;             // + h
    const float* eqb = eqa + HDIM;

    float ekc[4], ekn[4], eac[4], ean[4], ebc[4], ebn[4], wvc[4], wvn[4];
    #pragma unroll
    for (int j = 0; j < 4; j++) ekc[j] = ekp[(size_t)j * KLEN];
    *(float4*)&eac[0] = *(const float4*)(eqa);
    *(float4*)&ebc[0] = *(const float4*)(eqb);
    *(float4*)&wvc[0] = *(const float4*)(w_v);

    float acc0 = 0.f, acc1 = 0.f;
    for (int h0 = 0; h0 < HDIM; h0 += 4) {
        if (h0 < HDIM - 4) {                  // prefetch next 4-h chunk
            #pragma unroll
            for (int j = 0; j < 4; j++) ekn[j] = ekp[(size_t)(h0 + 4 + j) * KLEN];
            *(float4*)&ean[0] = *(const float4*)(eqa + h0 + 4);
            *(float4*)&ebn[0] = *(const float4*)(eqb + h0 + 4);
            *(float4*)&wvn[0] = *(const float4*)(w_v + h0 + 4);
        }
        #pragma unroll
        for (int j = 0; j < 4; j++) {
            float w2 = -2.0f * wvc[j];
            acc0 = fmaf(w2, __builtin_amdgcn_rcpf(fmaf(eac[j], ekc[j], 1.f)), acc0);
            acc1 = fmaf(w2, __builtin_amdgcn_rcpf(fmaf(ebc[j], ekc[j], 1.f)), acc1);
        }
        #pragma unroll
        for (int j = 0; j < 4; j++) {
            ekc[j] = ekn[j]; eac[j] = ean[j]; ebc[j] = ebn[j]; wvc[j] = wvn[j];
        }
    }

    {   // masked exp -> el[k][q0..q0+1]
        int kg = k0g + lane;
        float e0 = (kg < vlen) ? __expf(acc0) : 0.f;
        float e1 = (kg < vlen) ? __expf(acc1) : 0.f;
        *(float2*)(&el[lane][q0]) = make_float2(e0, e1);
    }
    __syncthreads();

    // ---- phase 2: E @ V, wave-exclusive 16-k slice ----
    int kw = wav << 4;
    int cnt = vlen - (k0g + kw); cnt = cnt < 0 ? 0 : (cnt > 16 ? 16 : cnt);
    int cnt4 = (cnt + 3) & ~3;                // el == 0 beyond vlen -> safe
    const float* vb = values + ((size_t)b * KLEN + k0g + kw) * DDIM + (lane << 2);

    float4 acc[8];
    float acct[8];
    #pragma unroll
    for (int q = 0; q < 8; q++) { acc[q] = make_float4(0.f, 0.f, 0.f, 0.f); acct[q] = 0.f; }

    for (int k = 0; k < cnt4; k += 4) {
        #pragma unroll
        for (int j = 0; j < 4; j++) {
            float4 v  = *(const float4*)(vb + (size_t)(k + j) * DDIM);
            float4 p0 = *(const float4*)(&el[kw + k + j][0]);
            float4 p1 = *(const float4*)(&el[kw + k + j][4]);
            float pq[8] = {p0.x, p0.y, p0.z, p0.w, p1.x, p1.y, p1.z, p1.w};
            #pragma unroll
            for (int q = 0; q < 8; q++) {
                acc[q].x = fmaf(pq[q], v.x, acc[q].x);
                acc[q].y = fmaf(pq[q], v.y, acc[q].y);
                acc[q].z = fmaf(pq[q], v.z, acc[q].z);
                acc[q].w = fmaf(pq[q], v.w, acc[q].w);
                acct[q] += pq[q];
            }
        }
    }

    // ---- cross-wave reduce: 4 barrier-serialized passes into accbuf ----
    __syncthreads();
    if (wav == 0) {
        #pragma unroll
        for (int q = 0; q < 8; q++)
            *(float4*)(&accbuf[q][lane << 2]) = acc[q];
        if (lane == 0) {
            #pragma unroll
            for (int q = 0; q < 8; q++) tacc[q] = acct[q];
        }
    }
    __syncthreads();
    #pragma unroll
    for (int w = 1; w < 4; w++) {
        if (wav == w) {
            #pragma unroll
            for (int q = 0; q < 8; q++) {
                float4 t = *(const float4*)(&accbuf[q][lane << 2]);
                t.x += acc[q].x; t.y += acc[q].y; t.z += acc[q].z; t.w += acc[q].w;
                *(float4*)(&accbuf[q][lane << 2]) = t;
            }
            if (lane == 0) {
                #pragma unroll
                for (int q = 0; q < 8; q++) tacc[q] += acct[q];
            }
        }
        __syncthreads();
    }

    #pragma unroll
    for (int e = 0; e < 2; e++) {
        int slot = (tid << 1) | e;            // 512 f4 slots
        int q = slot >> 6, d4 = slot & 63;
        *(float4*)(part + ((size_t)ks * 1024 + bq0 + q) * DDIM + (d4 << 2)) =
            *(const float4*)(&accbuf[q][d4 << 2]);
    }
    if (tid < 8) Tp[(size_t)ks * 1024 + bq0 + tid] = tacc[tid];
}

// ============ sum 16 ks-partials, normalize by T ============
__global__ __launch_bounds__(256) void combine_kernel(
    const float* __restrict__ part, const float* __restrict__ Tp,
    float* __restrict__ out)
{
    int i = blockIdx.x * 256 + threadIdx.x;        // 65536 float4 slots
    int row = i >> 6;                              // 0..1023 (b*64+q)
    const float4* p4 = (const float4*)part;
    float t = 0.f;
    #pragma unroll
    for (int j = 0; j < 16; j++) t += Tp[(size_t)j * 1024 + row];
    float inv = 1.0f / t;
    float4 a = p4[i];
    #pragma unroll
    for (int j = 1; j < 16; j++) {
        float4 v = p4[(size_t)j * 65536 + i];
        a.x += v.x; a.y += v.y; a.z += v.z; a.w += v.w;
    }
    a.x *= inv; a.y *= inv; a.z *= inv; a.w *= inv;
    ((float4*)out)[i] = a;
}

extern "C" void kernel_launch(void* const* d_in, const int* in_sizes, int n_in,
                              void* d_out, int out_size, void* d_ws, size_t ws_size,
                              hipStream_t stream) {
    const float* queries    = (const float*)d_in[0]; // [16,64,256]
    const float* keys       = (const float*)d_in[1]; // [16,1024,256]
    const float* values     = (const float*)d_in[2]; // [16,1024,256]
    const int*   valid_lens = (const int*)d_in[3];   // [16]
    const float* W_q        = (const float*)d_in[4]; // [256,128]
    const float* W_k        = (const float*)d_in[5]; // [256,128]
    const float* w_v        = (const float*)d_in[6]; // [128]

    float* Eq   = (float*)d_ws;            // 1024*128       = 512 KB
    float* Ek   = Eq + 131072;             // 16*128*1024    = 8 MB
    float* part = Ek + 2097152;            // 16*1024*256    = 16 MB
    float* Tp   = part + 4194304;          // 16*1024 floats = 64 KB

    proj_kernel<<<1088, 256, 0, stream>>>(queries, keys, W_q, W_k, Eq, Ek);
    score_av_kernel<<<2048, 256, 0, stream>>>(Eq, Ek, w_v, valid_lens, values, part, Tp);
    combine_kernel<<<256, 256, 0, stream>>>(part, Tp, (float*)d_out);
}

// Round 11
// 158.361 us; speedup vs baseline: 1.0196x; 1.0196x over previous
//
#include <hip/hip_runtime.h>

#define DDIM 256
#define HDIM 128
#define KLEN 1024
// 2*log2(e): exp2(SCL*x) == e^{2x}
#define SCL 2.8853900817779268f

// ============ Projection -> Eq/Ek = exp2(SCL * in@W) ============
// v2 (proven 33us): wave-uniform W (scalar s_load path) x per-lane rows.
// Block = 64 rows x 32 h = 4 waves; each wave owns 8 h, each lane owns 1 row.
// A-tile (64 rows x 64 d) in LDS, XOR-swizzled on 16B granules so each
// lane's ds_read_b128 of its own row is <=2-way (free). W operands are
// wave-uniform -> scalar loads, costing no VALU/VMEM/LDS bandwidth.
// Grid 1088 (4.25 blocks/CU): 1024 key blocks (XCD-swizzled) + 64 query.
// Output layouts: Eq row-major [row][128], Ek [b][h][k], exp2 applied.
__global__ __launch_bounds__(256) void proj_kernel(
    const float* __restrict__ queries, const float* __restrict__ keys,
    const float* __restrict__ W_q, const float* __restrict__ W_k,
    float* __restrict__ Eq, float* __restrict__ Ek)
{
    __shared__ union {
        float a[64 * 64];    // 16 KB A-tile (swizzled)
        float t[32][68];     // epilogue transpose staging (keys), pad 64->68
    } sm;

    const int tid  = threadIdx.x;
    const int lane = tid & 63;
    const int wav  = tid >> 6;

    int blk = blockIdx.x;
    bool iskey; int b = 0, kc0 = 0, hb, row0;
    const float* in; const float* W;
    if (blk < 1024) {
        iskey = true;
        int xcd = blk & 7, s = blk >> 3;
        b = ((s >> 6) << 3) | xcd;
        int r6 = s & 63;
        kc0 = (r6 >> 2) << 6;     // 16 k-chunks of 64
        hb  = (r6 & 3) << 5;      // 4 h-chunks of 32
        row0 = b * KLEN + kc0;
        in = keys; W = W_k;
    } else {
        iskey = false;
        int qrb = blk - 1024;     // 0..63
        row0 = (qrb >> 2) << 6;
        hb   = (qrb & 3) << 5;
        in = queries; W = W_q;
    }

    // wave-uniform h-base -> W accesses become scalar loads
    const int hg8 = __builtin_amdgcn_readfirstlane(wav << 3);
    const float* Wu = W + hb + hg8;

    // staging: 4 x 16B granules per thread per 64-d step, coalesced reads
    const int srow = tid >> 4;        // 0..15 (+16*i covers 64 rows)
    const int sgd  = tid & 15;        // 16B granule within 64-d row slice
    const float* gsrc = in + (size_t)(row0 + srow) * DDIM + (sgd << 2);

    float4 pf0 = *(const float4*)(gsrc);
    float4 pf1 = *(const float4*)(gsrc + 16 * DDIM);
    float4 pf2 = *(const float4*)(gsrc + 32 * DDIM);
    float4 pf3 = *(const float4*)(gsrc + 48 * DDIM);

    float acc[8];
    #pragma unroll
    for (int c = 0; c < 8; c++) acc[c] = 0.f;

    // XOR-swizzled LDS write offsets (float index): granule ^= (row & 7)
    const int w0 = (srow)      * 64 + ((sgd ^ ((srow)      & 7)) << 2);
    const int w1 = (srow + 16) * 64 + ((sgd ^ ((srow + 16) & 7)) << 2);
    const int w2 = (srow + 32) * 64 + ((sgd ^ ((srow + 32) & 7)) << 2);
    const int w3 = (srow + 48) * 64 + ((sgd ^ ((srow + 48) & 7)) << 2);

    for (int dt0 = 0; dt0 < DDIM; dt0 += 64) {
        *(float4*)(sm.a + w0) = pf0;
        *(float4*)(sm.a + w1) = pf1;
        *(float4*)(sm.a + w2) = pf2;
        *(float4*)(sm.a + w3) = pf3;
        __syncthreads();
        if (dt0 < DDIM - 64) {        // prefetch next d-tile under compute
            const float* g2 = gsrc + dt0 + 64;
            pf0 = *(const float4*)(g2);
            pf1 = *(const float4*)(g2 + 16 * DDIM);
            pf2 = *(const float4*)(g2 + 32 * DDIM);
            pf3 = *(const float4*)(g2 + 48 * DDIM);
        }
        const float* arow = sm.a + lane * 64;
        const int lx = lane & 7;
        #pragma unroll
        for (int d4 = 0; d4 < 64; d4 += 4) {
            float4 a = *(const float4*)(arow + ((((d4 >> 2)) ^ lx) << 2));
            const float* wr = Wu + (size_t)(dt0 + d4) * HDIM;
            #pragma unroll
            for (int c = 0; c < 8; c++) acc[c] = fmaf(a.x, wr[c],            acc[c]);
            #pragma unroll
            for (int c = 0; c < 8; c++) acc[c] = fmaf(a.y, wr[HDIM + c],     acc[c]);
            #pragma unroll
            for (int c = 0; c < 8; c++) acc[c] = fmaf(a.z, wr[2 * HDIM + c], acc[c]);
            #pragma unroll
            for (int c = 0; c < 8; c++) acc[c] = fmaf(a.w, wr[3 * HDIM + c], acc[c]);
        }
        __syncthreads();   // compute done before next tile overwrites LDS
    }

    float e[8];
    #pragma unroll
    for (int c = 0; c < 8; c++) e[c] = __builtin_amdgcn_exp2f(SCL * acc[c]);

    if (!iskey) {
        float* dst = Eq + (size_t)(row0 + lane) * HDIM + hb + hg8;
        *(float4*)(dst)     = make_float4(e[0], e[1], e[2], e[3]);
        *(float4*)(dst + 4) = make_float4(e[4], e[5], e[6], e[7]);
    } else {
        // transpose 64k x 32h -> t[h][k], then coalesced 256B-row stores
        #pragma unroll
        for (int c = 0; c < 8; c++) sm.t[(wav << 3) + c][lane] = e[c];
        __syncthreads();
        float* dstb = Ek + (size_t)b * HDIM * KLEN + (size_t)hb * KLEN + kc0;
        #pragma unroll
        for (int i = 0; i < 2; i++) {
            int g = tid + (i << 8);
            int h = g >> 4, k4 = (g & 15) << 2;
            float4 o = *(const float4*)(&sm.t[h][k4]);
            *(float4*)(dstb + (size_t)h * KLEN + k4) = o;
        }
    }
}

// ============ FUSED scores + E@V v4 (normalization-free) ============
// R10 lesson: keep R8's proven phase-1 regime (8-deep float2 Ek stream +
// LDS-broadcast eqw); v3's dword stream + global eq + K-split regressed.
// v4 splits Q not K: grid 2048 = (16 b x 16 qt of 4 q x 8 kq of 128 k),
// XCD-matched to proj's Ek[b]; part stays 8 slices (no extra traffic).
// Wave = 1 q (phase-1 chain HALF of R8); LDS 8.3 KB (eqw float2 union'd
// with accbuf; no 32KB slab) -> 8 blocks/CU via __launch_bounds__(256,8),
// 32 waves/CU target. vlen-skip keeps working, now with backfill.
// Phase 2: wave owns exclusive 32 k; per k one coalesced 1KB/wave V row +
// one broadcast b128 el read -> 16 fma + 4 T-adds. 4-pass serialized
// cross-wave reduce into accbuf. Softmax algebra: Sum(w) const and
// max-shift cancel in (E@V)/T; |s|<~25 -> fp32-safe. Unconditional
// stores -> poison-safe.
__global__ __launch_bounds__(256, 8) void score_av_kernel(
    const float* __restrict__ Eq, const float* __restrict__ Ek,
    const float* __restrict__ w_v, const int* __restrict__ valid_lens,
    const float* __restrict__ values,
    float* __restrict__ part, float* __restrict__ Tp)
{
    __shared__ union {
        float2 eqw[4][HDIM];       // (eq_q, -2w) per wave's q      4 KB
        float  accbuf[4][256];     // block O accumulator           4 KB
    } u;
    __shared__ float el[128][8];   // E tile [k][4q + pad]          4 KB
    __shared__ float tacc[4];

    const int tid = threadIdx.x;
    const int lane = tid & 63, wav = tid >> 6;
    int blk = blockIdx.x;
    int xcd = blk & 7, s = blk >> 3;          // 0..255
    int b = ((s >> 7) << 3) | xcd;            // XCD-matched to proj's Ek[b]
    int r = s & 127;
    int qt = r >> 3, kq = r & 7;              // qt 0..15 (4q), kq 0..7 (128k)
    int bq0 = b * 64 + qt * 4;
    int k0g = kq << 7;
    int vlen = valid_lens[b];

    if (k0g >= vlen) {                        // fully-masked slice: zeros
        int q = tid >> 6, d4 = tid & 63;      // 256 f4 slots, 1/thread
        *(float4*)(part + ((size_t)kq * 1024 + bq0 + q) * DDIM + (d4 << 2)) =
            make_float4(0.f, 0.f, 0.f, 0.f);
        if (tid < 4) Tp[(size_t)kq * 1024 + bq0 + tid] = 0.f;
        return;
    }

    // ---- prologue: pack eqw (coalesced one-time global reads) ----
    #pragma unroll
    for (int i = 0; i < 2; i++) {
        int slot = tid + (i << 8);            // 512 slots = 4 q x 128 h
        int w = slot >> 7, h = slot & 127;
        u.eqw[w][h] = make_float2(Eq[(size_t)(bq0 + w) * HDIM + h],
                                  -2.0f * w_v[h]);
    }
    __syncthreads();

    // ---- phase 1: 1 q x 2 k per thread, 8-deep float2 reg dbuf (R8 regime) ----
    const int kl = lane << 1;
    const float* ekp = Ek + (size_t)b * HDIM * KLEN + k0g + kl;
    float2 buf[8];
    #pragma unroll
    for (int j = 0; j < 8; j++)
        buf[j] = *(const float2*)(ekp + (size_t)j * KLEN);

    float accx = 0.f, accy = 0.f;
    for (int h0 = 0; h0 < HDIM; h0 += 8) {
        float2 nxt[8];
        if (h0 < HDIM - 8) {
            #pragma unroll
            for (int j = 0; j < 8; j++)
                nxt[j] = *(const float2*)(ekp + (size_t)(h0 + 8 + j) * KLEN);
        }
        #pragma unroll
        for (int j = 0; j < 8; j++) {
            float2 e  = u.eqw[wav][h0 + j];
            float2 ek = buf[j];
            accx = fmaf(e.y, __builtin_amdgcn_rcpf(fmaf(e.x, ek.x, 1.f)), accx);
            accy = fmaf(e.y, __builtin_amdgcn_rcpf(fmaf(e.x, ek.y, 1.f)), accy);
        }
        #pragma unroll
        for (int j = 0; j < 8; j++) buf[j] = nxt[j];
    }

    {   // masked exp -> el[k][wav]
        int kg = k0g + kl;
        el[kl][wav]     = (kg     < vlen) ? __expf(accx) : 0.f;
        el[kl + 1][wav] = (kg + 1 < vlen) ? __expf(accy) : 0.f;
    }
    __syncthreads();

    // ---- phase 2: E @ V, wave-exclusive 32-k slice ----
    int kw = wav << 5;
    int cnt = vlen - (k0g + kw); cnt = cnt < 0 ? 0 : (cnt > 32 ? 32 : cnt);
    int cnt4 = (cnt + 3) & ~3;                // el == 0 beyond vlen -> safe
    const float* vb = values + ((size_t)b * KLEN + k0g + kw) * DDIM + (lane << 2);

    float4 acc[4];
    float acct[4];
    #pragma unroll
    for (int q = 0; q < 4; q++) { acc[q] = make_float4(0.f, 0.f, 0.f, 0.f); acct[q] = 0.f; }

    for (int k = 0; k < cnt4; k += 4) {
        #pragma unroll
        for (int j = 0; j < 4; j++) {
            float4 v = *(const float4*)(vb + (size_t)(k + j) * DDIM);
            float4 p = *(const float4*)(&el[kw + k + j][0]);
            float pq[4] = {p.x, p.y, p.z, p.w};
            #pragma unroll
            for (int q = 0; q < 4; q++) {
                acc[q].x = fmaf(pq[q], v.x, acc[q].x);
                acc[q].y = fmaf(pq[q], v.y, acc[q].y);
                acc[q].z = fmaf(pq[q], v.z, acc[q].z);
                acc[q].w = fmaf(pq[q], v.w, acc[q].w);
                acct[q] += pq[q];
            }
        }
    }

    // ---- cross-wave reduce: serialized passes into accbuf (eqw dead) ----
    __syncthreads();
    if (wav == 0) {
        #pragma unroll
        for (int q = 0; q < 4; q++)
            *(float4*)(&u.accbuf[q][lane << 2]) = acc[q];
        if (lane == 0) {
            #pragma unroll
            for (int q = 0; q < 4; q++) tacc[q] = acct[q];
        }
    }
    __syncthreads();
    #pragma unroll
    for (int w = 1; w < 4; w++) {
        if (wav == w) {
            #pragma unroll
            for (int q = 0; q < 4; q++) {
                float4 t = *(const float4*)(&u.accbuf[q][lane << 2]);
                t.x += acc[q].x; t.y += acc[q].y; t.z += acc[q].z; t.w += acc[q].w;
                *(float4*)(&u.accbuf[q][lane << 2]) = t;
            }
            if (lane == 0) {
                #pragma unroll
                for (int q = 0; q < 4; q++) tacc[q] += acct[q];
            }
        }
        __syncthreads();
    }

    {   // 256 f4 output slots, 1/thread
        int q = tid >> 6, d4 = tid & 63;
        *(float4*)(part + ((size_t)kq * 1024 + bq0 + q) * DDIM + (d4 << 2)) =
            *(const float4*)(&u.accbuf[q][d4 << 2]);
    }
    if (tid < 4) Tp[(size_t)kq * 1024 + bq0 + tid] = tacc[tid];
}

// ============ sum 8 kq-partials, normalize by T ============
__global__ __launch_bounds__(256) void combine_kernel(
    const float* __restrict__ part, const float* __restrict__ Tp,
    float* __restrict__ out)
{
    int i = blockIdx.x * 256 + threadIdx.x;        // 65536 float4 slots
    int row = i >> 6;                              // 0..1023 (b*64+q)
    const float4* p4 = (const float4*)part;
    float t = 0.f;
    #pragma unroll
    for (int j = 0; j < 8; j++) t += Tp[(size_t)j * 1024 + row];
    float inv = 1.0f / t;
    float4 a = p4[i];
    #pragma unroll
    for (int j = 1; j < 8; j++) {
        float4 v = p4[(size_t)j * 65536 + i];
        a.x += v.x; a.y += v.y; a.z += v.z; a.w += v.w;
    }
    a.x *= inv; a.y *= inv; a.z *= inv; a.w *= inv;
    ((float4*)out)[i] = a;
}

extern "C" void kernel_launch(void* const* d_in, const int* in_sizes, int n_in,
                              void* d_out, int out_size, void* d_ws, size_t ws_size,
                              hipStream_t stream) {
    const float* queries    = (const float*)d_in[0]; // [16,64,256]
    const float* keys       = (const float*)d_in[1]; // [16,1024,256]
    const float* values     = (const float*)d_in[2]; // [16,1024,256]
    const int*   valid_lens = (const int*)d_in[3];   // [16]
    const float* W_q        = (const float*)d_in[4]; // [256,128]
    const float* W_k        = (const float*)d_in[5]; // [256,128]
    const float* w_v        = (const float*)d_in[6]; // [128]

    float* Eq   = (float*)d_ws;            // 1024*128      = 512 KB
    float* Ek   = Eq + 131072;             // 16*128*1024   = 8 MB
    float* part = Ek + 2097152;            // 8*1024*256    = 8 MB
    float* Tp   = part + 2097152;          // 8*1024 floats = 32 KB

    proj_kernel<<<1088, 256, 0, stream>>>(queries, keys, W_q, W_k, Eq, Ek);
    score_av_kernel<<<2048, 256, 0, stream>>>(Eq, Ek, w_v, valid_lens, values, part, Tp);
    combine_kernel<<<256, 256, 0, stream>>>(part, Tp, (float*)d_out);
}

// Round 12
// 136.120 us; speedup vs baseline: 1.1861x; 1.1634x over previous
//
#include <hip/hip_runtime.h>

#define DDIM 256
#define HDIM 128
#define KLEN 1024
// 2*log2(e): exp2(SCL*x) == e^{2x}
#define SCL 2.8853900817779268f

// ============ Projection -> Eq/Ek = exp2(SCL * in@W) ============
// v2 (proven 33us): wave-uniform W (scalar s_load path) x per-lane rows.
// Block = 64 rows x 32 h = 4 waves; each wave owns 8 h, each lane owns 1 row.
// A-tile (64 rows x 64 d) in LDS, XOR-swizzled on 16B granules so each
// lane's ds_read_b128 of its own row is <=2-way (free). W operands are
// wave-uniform -> scalar loads, costing no VALU/VMEM/LDS bandwidth.
// FMA:LDS-instr = 32:1 (>=24 needed to clear the per-CU LDS pipe) -- the
// only proj structure of six tried that is not LDS-issue- or latency-bound
// beyond this plateau.
// Grid 1088 (4.25 blocks/CU): 1024 key blocks (XCD-swizzled) + 64 query.
// Output layouts: Eq row-major [row][128], Ek [b][h][k], exp2 applied.
__global__ __launch_bounds__(256) void proj_kernel(
    const float* __restrict__ queries, const float* __restrict__ keys,
    const float* __restrict__ W_q, const float* __restrict__ W_k,
    float* __restrict__ Eq, float* __restrict__ Ek)
{
    __shared__ union {
        float a[64 * 64];    // 16 KB A-tile (swizzled)
        float t[32][68];     // epilogue transpose staging (keys), pad 64->68
    } sm;

    const int tid  = threadIdx.x;
    const int lane = tid & 63;
    const int wav  = tid >> 6;

    int blk = blockIdx.x;
    bool iskey; int b = 0, kc0 = 0, hb, row0;
    const float* in; const float* W;
    if (blk < 1024) {
        iskey = true;
        int xcd = blk & 7, s = blk >> 3;
        b = ((s >> 6) << 3) | xcd;
        int r6 = s & 63;
        kc0 = (r6 >> 2) << 6;     // 16 k-chunks of 64
        hb  = (r6 & 3) << 5;      // 4 h-chunks of 32
        row0 = b * KLEN + kc0;
        in = keys; W = W_k;
    } else {
        iskey = false;
        int qrb = blk - 1024;     // 0..63
        row0 = (qrb >> 2) << 6;
        hb   = (qrb & 3) << 5;
        in = queries; W = W_q;
    }

    // wave-uniform h-base -> W accesses become scalar loads
    const int hg8 = __builtin_amdgcn_readfirstlane(wav << 3);
    const float* Wu = W + hb + hg8;

    // staging: 4 x 16B granules per thread per 64-d step, coalesced reads
    const int srow = tid >> 4;        // 0..15 (+16*i covers 64 rows)
    const int sgd  = tid & 15;        // 16B granule within 64-d row slice
    const float* gsrc = in + (size_t)(row0 + srow) * DDIM + (sgd << 2);

    float4 pf0 = *(const float4*)(gsrc);
    float4 pf1 = *(const float4*)(gsrc + 16 * DDIM);
    float4 pf2 = *(const float4*)(gsrc + 32 * DDIM);
    float4 pf3 = *(const float4*)(gsrc + 48 * DDIM);

    float acc[8];
    #pragma unroll
    for (int c = 0; c < 8; c++) acc[c] = 0.f;

    // XOR-swizzled LDS write offsets (float index): granule ^= (row & 7)
    const int w0 = (srow)      * 64 + ((sgd ^ ((srow)      & 7)) << 2);
    const int w1 = (srow + 16) * 64 + ((sgd ^ ((srow + 16) & 7)) << 2);
    const int w2 = (srow + 32) * 64 + ((sgd ^ ((srow + 32) & 7)) << 2);
    const int w3 = (srow + 48) * 64 + ((sgd ^ ((srow + 48) & 7)) << 2);

    for (int dt0 = 0; dt0 < DDIM; dt0 += 64) {
        *(float4*)(sm.a + w0) = pf0;
        *(float4*)(sm.a + w1) = pf1;
        *(float4*)(sm.a + w2) = pf2;
        *(float4*)(sm.a + w3) = pf3;
        __syncthreads();
        if (dt0 < DDIM - 64) {        // prefetch next d-tile under compute
            const float* g2 = gsrc + dt0 + 64;
            pf0 = *(const float4*)(g2);
            pf1 = *(const float4*)(g2 + 16 * DDIM);
            pf2 = *(const float4*)(g2 + 32 * DDIM);
            pf3 = *(const float4*)(g2 + 48 * DDIM);
        }
        const float* arow = sm.a + lane * 64;
        const int lx = lane & 7;
        #pragma unroll
        for (int d4 = 0; d4 < 64; d4 += 4) {
            float4 a = *(const float4*)(arow + ((((d4 >> 2)) ^ lx) << 2));
            const float* wr = Wu + (size_t)(dt0 + d4) * HDIM;
            #pragma unroll
            for (int c = 0; c < 8; c++) acc[c] = fmaf(a.x, wr[c],            acc[c]);
            #pragma unroll
            for (int c = 0; c < 8; c++) acc[c] = fmaf(a.y, wr[HDIM + c],     acc[c]);
            #pragma unroll
            for (int c = 0; c < 8; c++) acc[c] = fmaf(a.z, wr[2 * HDIM + c], acc[c]);
            #pragma unroll
            for (int c = 0; c < 8; c++) acc[c] = fmaf(a.w, wr[3 * HDIM + c], acc[c]);
        }
        __syncthreads();   // compute done before next tile overwrites LDS
    }

    float e[8];
    #pragma unroll
    for (int c = 0; c < 8; c++) e[c] = __builtin_amdgcn_exp2f(SCL * acc[c]);

    if (!iskey) {
        float* dst = Eq + (size_t)(row0 + lane) * HDIM + hb + hg8;
        *(float4*)(dst)     = make_float4(e[0], e[1], e[2], e[3]);
        *(float4*)(dst + 4) = make_float4(e[4], e[5], e[6], e[7]);
    } else {
        // transpose 64k x 32h -> t[h][k], then coalesced 256B-row stores
        #pragma unroll
        for (int c = 0; c < 8; c++) sm.t[(wav << 3) + c][lane] = e[c];
        __syncthreads();
        float* dstb = Ek + (size_t)b * HDIM * KLEN + (size_t)hb * KLEN + kc0;
        #pragma unroll
        for (int i = 0; i < 2; i++) {
            int g = tid + (i << 8);
            int h = g >> 4, k4 = (g & 15) << 2;
            float4 o = *(const float4*)(&sm.t[h][k4]);
            *(float4*)(dstb + (size_t)h * KLEN + k4) = o;
        }
    }
}

// ============ FUSED scores + E@V (normalization-free) ============
// Measured-best (R7/R8: 43us, VALUBusy 37%). Grid 1024 = (16 b x 8 qt x
// 8 kq), XCD-matched to proj's Ek[b] placement; 256 thr (4 waves).
// Phase 1 (score): thread = 2q x 2k over all 128 h; Ek streamed from L2
// (coalesced 512B/wave float2 loads, 8-deep reg dual-buffer); (eq0,eq1,w2)
// as ONE broadcast float4/h from LDS. E tile (8q x 128k, masked-zero exp)
// -> 4 KB LDS. One barrier.
// Phase 2 (E@V): wave owns exclusive 32 k; per k one fully-coalesced
// 1KB/wave V float4 row + 2 broadcast b128 E reads -> 32 fma + 8 T-adds
// (wave-uniform). Slab reduce -> part[kq] + Tp[kq].
// Softmax algebra: Sum(w) constant and max-shift cancel in (E@V)/T;
// |s|<~25 -> exp fp32-safe. Unconditional stores -> poison-safe.
// NOTE (R9-R11): vlen block-skip, K-split x16 and Q-split x16 variants all
// measured neutral-to-worse (137.7 / 161.5 / 158.4) -- makespan is set by
// max-loaded CU, not total work, at small grid/CU ratios. Keep this form.
__global__ __launch_bounds__(256) void score_av_kernel(
    const float* __restrict__ Eq, const float* __restrict__ Ek,
    const float* __restrict__ w_v, const int* __restrict__ valid_lens,
    const float* __restrict__ values,
    float* __restrict__ part, float* __restrict__ Tp)
{
    __shared__ union {
        struct {
            float4 eqw[4][HDIM];   // (eq_q0, eq_q1, -2w, 0) per wave  8 KB
            float  el[128][8];     // E tile [k][q]                    4 KB
        } p;
        float4 slab[4][8][64];     // 32 KB cross-wave reduce
    } sm;
    __shared__ float tslab[4][8];

    const int tid = threadIdx.x;
    const int lane = tid & 63, wav = tid >> 6;
    int blk = blockIdx.x;
    int xcd = blk & 7, s = blk >> 3;          // 0..127
    int b = ((s >> 6) << 3) | xcd;
    int r = s & 63;
    int qt = r >> 3, kq = r & 7;
    int bq0 = b * 64 + qt * 8;
    int k0g = kq << 7;                        // global k base of 128-slice
    int vlen = valid_lens[b];

    // ---- prologue: pack eqw (coalesced one-time global reads) ----
    #pragma unroll
    for (int i = 0; i < 2; i++) {
        int slot = tid + (i << 8);            // 512 slots = 4 waves x 128 h
        int w = slot >> 7, h = slot & 127;
        sm.p.eqw[w][h] = make_float4(
            Eq[(size_t)(bq0 + 2 * w) * HDIM + h],
            Eq[(size_t)(bq0 + 2 * w + 1) * HDIM + h],
            -2.0f * w_v[h], 0.f);
    }
    __syncthreads();

    // ---- phase 1: scores for (2q x 2k), h-streamed, 8-deep reg dbuf ----
    const int kl = lane << 1;                 // lane's 2 k within slice
    const float* ekp = Ek + (size_t)b * HDIM * KLEN + k0g + kl;
    float2 buf[8];
    #pragma unroll
    for (int j = 0; j < 8; j++)
        buf[j] = *(const float2*)(ekp + (size_t)j * KLEN);

    float2 acc0 = make_float2(0.f, 0.f), acc1 = make_float2(0.f, 0.f);
    for (int h0 = 0; h0 < HDIM; h0 += 8) {
        float2 nxt[8];
        if (h0 < HDIM - 8) {
            #pragma unroll
            for (int j = 0; j < 8; j++)
                nxt[j] = *(const float2*)(ekp + (size_t)(h0 + 8 + j) * KLEN);
        }
        #pragma unroll
        for (int j = 0; j < 8; j++) {
            float4 e = sm.p.eqw[wav][h0 + j];
            float2 ek = buf[j];
            acc0.x = fmaf(e.z, __builtin_amdgcn_rcpf(fmaf(e.x, ek.x, 1.f)), acc0.x);
            acc0.y = fmaf(e.z, __builtin_amdgcn_rcpf(fmaf(e.x, ek.y, 1.f)), acc0.y);
            acc1.x = fmaf(e.z, __builtin_amdgcn_rcpf(fmaf(e.y, ek.x, 1.f)), acc1.x);
            acc1.y = fmaf(e.z, __builtin_amdgcn_rcpf(fmaf(e.y, ek.y, 1.f)), acc1.y);
        }
        #pragma unroll
        for (int j = 0; j < 8; j++) buf[j] = nxt[j];
    }

    {   // masked exp -> E tile in LDS (el[k][q]); one-time write
        int kg = k0g + kl;
        float e00 = (kg     < vlen) ? __expf(acc0.x) : 0.f;   // q0, k
        float e01 = (kg + 1 < vlen) ? __expf(acc0.y) : 0.f;   // q0, k+1
        float e10 = (kg     < vlen) ? __expf(acc1.x) : 0.f;   // q1, k
        float e11 = (kg + 1 < vlen) ? __expf(acc1.y) : 0.f;   // q1, k+1
        *(float2*)(&sm.p.el[kl][2 * wav])     = make_float2(e00, e10);
        *(float2*)(&sm.p.el[kl + 1][2 * wav]) = make_float2(e01, e11);
    }
    __syncthreads();

    // ---- phase 2: E @ V, wave-exclusive 32-k slice ----
    int kw = wav << 5;                        // wave's k-local base
    int kg0 = k0g + kw;
    int cnt = vlen - kg0; cnt = cnt < 0 ? 0 : (cnt > 32 ? 32 : cnt);
    int cnt4 = (cnt + 3) & ~3;                // el == 0 beyond vlen -> safe
    const float* vb = values + ((size_t)b * KLEN + kg0) * DDIM + (lane << 2);

    float4 acc[8];
    float acct[8];
    #pragma unroll
    for (int q = 0; q < 8; q++) { acc[q] = make_float4(0.f, 0.f, 0.f, 0.f); acct[q] = 0.f; }

    for (int k = 0; k < cnt4; k += 4) {
        #pragma unroll
        for (int j = 0; j < 4; j++) {
            float4 v  = *(const float4*)(vb + (size_t)(k + j) * DDIM);
            float4 p0 = *(const float4*)(&sm.p.el[kw + k + j][0]);
            float4 p1 = *(const float4*)(&sm.p.el[kw + k + j][4]);
            float pq[8] = {p0.x, p0.y, p0.z, p0.w, p1.x, p1.y, p1.z, p1.w};
            #pragma unroll
            for (int q = 0; q < 8; q++) {
                acc[q].x = fmaf(pq[q], v.x, acc[q].x);
                acc[q].y = fmaf(pq[q], v.y, acc[q].y);
                acc[q].z = fmaf(pq[q], v.z, acc[q].z);
                acc[q].w = fmaf(pq[q], v.w, acc[q].w);
                acct[q] += pq[q];
            }
        }
    }

    __syncthreads();               // el reads done; overwrite with slab
    #pragma unroll
    for (int q = 0; q < 8; q++) sm.slab[wav][q][lane] = acc[q];
    if (lane == 0) {
        #pragma unroll
        for (int q = 0; q < 8; q++) tslab[wav][q] = acct[q];
    }
    __syncthreads();
    #pragma unroll
    for (int e = 0; e < 2; e++) {
        int slot = (tid << 1) | e;         // 512 output f4 slots
        int q = slot >> 6, d4 = slot & 63;
        float4 a = sm.slab[0][q][d4];
        #pragma unroll
        for (int g = 1; g < 4; g++) {
            float4 t = sm.slab[g][q][d4];
            a.x += t.x; a.y += t.y; a.z += t.z; a.w += t.w;
        }
        *(float4*)(part + ((size_t)kq * 1024 + bq0 + q) * DDIM + (d4 << 2)) = a;
    }
    if (tid < 8) {
        float t = tslab[0][tid] + tslab[1][tid] + tslab[2][tid] + tslab[3][tid];
        Tp[(size_t)kq * 1024 + bq0 + tid] = t;
    }
}

// ============ sum 8 kq-partials, normalize by T ============
__global__ __launch_bounds__(256) void combine_kernel(
    const float* __restrict__ part, const float* __restrict__ Tp,
    float* __restrict__ out)
{
    int i = blockIdx.x * 256 + threadIdx.x;        // 65536 float4 slots
    int row = i >> 6;                              // 0..1023 (b*64+q)
    const float4* p4 = (const float4*)part;
    float t = 0.f;
    #pragma unroll
    for (int j = 0; j < 8; j++) t += Tp[(size_t)j * 1024 + row];
    float inv = 1.0f / t;
    float4 a = p4[i];
    #pragma unroll
    for (int j = 1; j < 8; j++) {
        float4 v = p4[(size_t)j * 65536 + i];
        a.x += v.x; a.y += v.y; a.z += v.z; a.w += v.w;
    }
    a.x *= inv; a.y *= inv; a.z *= inv; a.w *= inv;
    ((float4*)out)[i] = a;
}

extern "C" void kernel_launch(void* const* d_in, const int* in_sizes, int n_in,
                              void* d_out, int out_size, void* d_ws, size_t ws_size,
                              hipStream_t stream) {
    const float* queries    = (const float*)d_in[0]; // [16,64,256]
    const float* keys       = (const float*)d_in[1]; // [16,1024,256]
    const float* values     = (const float*)d_in[2]; // [16,1024,256]
    const int*   valid_lens = (const int*)d_in[3];   // [16]
    const float* W_q        = (const float*)d_in[4]; // [256,128]
    const float* W_k        = (const float*)d_in[5]; // [256,128]
    const float* w_v        = (const float*)d_in[6]; // [128]

    float* Eq   = (float*)d_ws;            // 1024*128      = 512 KB
    float* Ek   = Eq + 131072;             // 16*128*1024   = 8 MB
    float* part = Ek + 2097152;            // 8*1024*256    = 8 MB (no alias: Ek live)
    float* Tp   = part + 2097152;          // 8*1024 floats = 32 KB

    proj_kernel<<<1088, 256, 0, stream>>>(queries, keys, W_q, W_k, Eq, Ek);
    score_av_kernel<<<1024, 256, 0, stream>>>(Eq, Ek, w_v, valid_lens, values, part, Tp);
    combine_kernel<<<256, 256, 0, stream>>>(part, Tp, (float*)d_out);
}